// Round 5
// baseline (145.549 us; speedup 1.0000x reference)
//
#include <hip/hip_runtime.h>
#include <math.h>

#define BLOCK 256
#define UNROLL 8
#define TILE (BLOCK * UNROLL)     // 2048 elements per block, contiguous

// theta^2 for rel = qinv(a) * idd.
// rel is (nearly) unit-norm, so atan2(|v|, w) == acos(w / |rel|).
// Hastings acos approx, max abs err ~6.8e-5 rad (tolerance is 2% relative).
__device__ __forceinline__ float theta_sq(float4 qa, float4 qb) {
    float w1 = qa.x, x1 = -qa.y, y1 = -qa.z, z1 = -qa.w;
    float w2 = qb.x, x2 = qb.y,  y2 = qb.z,  z2 = qb.w;
    float w  = w1*w2 - (x1*x2 + y1*y2 + z1*z2);
    float vx = w1*x2 + w2*x1 + (y1*z2 - z1*y2);
    float vy = w1*y2 + w2*y1 + (z1*x2 - x1*z2);
    float vz = w1*z2 + w2*z1 + (x1*y2 - y1*x2);
    float nv2 = vx*vx + vy*vy + vz*vz;
    if (nv2 < 1e-12f) {                  // reference small-angle branch (nv < 1e-6)
        float s = 2.0f / w;
        return nv2 * s * s;
    }
    float rn = rsqrtf(w*w + nv2);        // exact normalize (~1.0)
    float c  = w * rn;                   // cos(theta/2) in [-1,1]
    float ac = fabsf(c);
    float p  = ((-0.0187293f*ac + 0.0742610f)*ac - 0.2121144f)*ac + 1.5707288f;
    float r  = sqrtf(fmaxf(1.0f - ac, 0.0f)) * p;            // acos(|c|)
    float acosc = (c >= 0.0f) ? r : (3.14159265358979f - r);
    float theta = 2.0f * acosc;
    return theta * theta;
}

// Round 4: same experiment as R3, compilable mechanics.
// - 16x asm-volatile global_load_dwordx4 (SADDR form: shared voffset VGPR,
//   uniform SGPR base per k) -> volatile asms keep their mutual order, so the
//   whole clause issues before the wait. 64 payload VGPRs live.
// - s_waitcnt vmcnt(0) + sched_barrier(0) (rule-#18 fence), then per-COMPONENT
//   empty keep-alive asms (32-bit operands only -- gfx950 rejects tied tuple
//   operands). Volatile ordering puts them after the wait; the compute's data
//   deps flow through them, so no compute can hoist above the wait.
__global__ __launch_bounds__(BLOCK, 4) void geo_loss_kernel(
        const float4* __restrict__ a,
        const float4* __restrict__ idd,
        float* __restrict__ partials, int n) {
    const int tid  = threadIdx.x;
    const int blk  = blockIdx.x * TILE;
    const int base = blk + tid;
    float acc = 0.0f;

    if (base + (UNROLL - 1) * BLOCK < n) {
        float4 qa[UNROLL], qb[UNROLL];
        const float4* sa = a + blk;       // uniform -> SGPR pair
        const float4* sb = idd + blk;     // uniform -> SGPR pair
        unsigned voff = (unsigned)tid * 16u;  // per-lane byte offset, 1 VGPR
        #pragma unroll
        for (int k = 0; k < UNROLL; k++) {
            asm volatile("global_load_dwordx4 %0, %1, %2"
                         : "=v"(qa[k]) : "v"(voff), "s"(sa + k * BLOCK));
            asm volatile("global_load_dwordx4 %0, %1, %2"
                         : "=v"(qb[k]) : "v"(voff), "s"(sb + k * BLOCK));
        }
        asm volatile("s_waitcnt vmcnt(0)" ::: "memory");
        __builtin_amdgcn_sched_barrier(0);
        #pragma unroll
        for (int k = 0; k < UNROLL; k++) {
            asm volatile("" : "+v"(qa[k].x), "+v"(qa[k].y),
                             "+v"(qa[k].z), "+v"(qa[k].w));
            asm volatile("" : "+v"(qb[k].x), "+v"(qb[k].y),
                             "+v"(qb[k].z), "+v"(qb[k].w));
        }
        #pragma unroll
        for (int k = 0; k < UNROLL; k++) acc += theta_sq(qa[k], qb[k]);
    } else {
        for (int k = 0; k < UNROLL; k++) {
            int idx = base + k * BLOCK;
            if (idx < n) acc += theta_sq(a[idx], idd[idx]);
        }
    }

    // wave-64 reduction
    #pragma unroll
    for (int off = 32; off > 0; off >>= 1)
        acc += __shfl_down(acc, off, 64);
    __shared__ float smem[BLOCK / 64];
    int lane = tid & 63;
    int wid  = tid >> 6;
    if (lane == 0) smem[wid] = acc;
    __syncthreads();
    if (tid == 0) {
        float s = 0.0f;
        #pragma unroll
        for (int i = 0; i < BLOCK / 64; i++) s += smem[i];
        partials[blockIdx.x] = s;
    }
}

__global__ __launch_bounds__(256) void finalize_kernel(
        const float* __restrict__ partials,
        float* __restrict__ out, int nparts) {
    float acc = 0.0f;
    for (int i = threadIdx.x; i < nparts; i += 256)
        acc += partials[i];
    #pragma unroll
    for (int off = 32; off > 0; off >>= 1)
        acc += __shfl_down(acc, off, 64);
    __shared__ float smem[4];
    int lane = threadIdx.x & 63;
    int wid  = threadIdx.x >> 6;
    if (lane == 0) smem[wid] = acc;
    __syncthreads();
    if (threadIdx.x == 0)
        out[0] = sqrtf(smem[0] + smem[1] + smem[2] + smem[3]);
}

extern "C" void kernel_launch(void* const* d_in, const int* in_sizes, int n_in,
                              void* d_out, int out_size, void* d_ws, size_t ws_size,
                              hipStream_t stream) {
    const float4* a   = (const float4*)d_in[0];
    const float4* idd = (const float4*)d_in[1];
    int n = in_sizes[0] / 4;             // 4,000,000 quaternions
    float* ws = (float*)d_ws;

    int grid = (n + TILE - 1) / TILE;    // 1954 blocks
    geo_loss_kernel<<<grid, BLOCK, 0, stream>>>(a, idd, ws, n);
    finalize_kernel<<<1, 256, 0, stream>>>(ws, (float*)d_out, grid);
}

// Round 7
// 135.266 us; speedup vs baseline: 1.0760x; 1.0760x over previous
//
#include <hip/hip_runtime.h>
#include <math.h>

#define BLOCK 256
#define UNROLL 4
#define TILE (BLOCK * UNROLL)     // 1024 elements per tile, contiguous
#define MAX_GRID 2048             // 8 blocks/CU * 256 CUs -> all resident

// clang ext-vector alias: bit-identical to float4, accepted by
// __builtin_nontemporal_load (HIP_vector_type is a struct and is rejected).
typedef float vf4 __attribute__((ext_vector_type(4)));

// theta^2 for rel = qinv(a) * idd.
// rel is (nearly) unit-norm, so atan2(|v|, w) == acos(w / |rel|).
// Hastings acos approx, max abs err ~6.8e-5 rad (tolerance is 2% relative).
__device__ __forceinline__ float theta_sq(vf4 qa, vf4 qb) {
    float w1 = qa.x, x1 = -qa.y, y1 = -qa.z, z1 = -qa.w;
    float w2 = qb.x, x2 = qb.y,  y2 = qb.z,  z2 = qb.w;
    float w  = w1*w2 - (x1*x2 + y1*y2 + z1*z2);
    float vx = w1*x2 + w2*x1 + (y1*z2 - z1*y2);
    float vy = w1*y2 + w2*y1 + (z1*x2 - x1*z2);
    float vz = w1*z2 + w2*z1 + (x1*y2 - y1*x2);
    float nv2 = vx*vx + vy*vy + vz*vz;
    if (nv2 < 1e-12f) {                  // reference small-angle branch (nv < 1e-6)
        float s = 2.0f / w;
        return nv2 * s * s;
    }
    float rn = rsqrtf(w*w + nv2);        // exact normalize (~1.0)
    float c  = w * rn;                   // cos(theta/2) in [-1,1]
    float ac = fabsf(c);
    float p  = ((-0.0187293f*ac + 0.0742610f)*ac - 0.2121144f)*ac + 1.5707288f;
    float r  = sqrtf(fmaxf(1.0f - ac, 0.0f)) * p;            // acos(|c|)
    float acosc = (c >= 0.0f) ? r : (3.14159265358979f - r);
    float theta = 2.0f * acosc;
    return theta * theta;
}

// Round 7: single-variable experiment on the R1 textbook base — NONTEMPORAL
// loads (retry of R6 with ext_vector_type to satisfy the builtin's pointer
// requirement). Established so far: kernel is throughput-capped at ~5 B/cyc/CU
// (3.07 TB/s) independent of occupancy (34-59%) and per-wave MLP (VGPR 24-48),
// with L3-resident replays equally slow -> cap is on the read-return path,
// not HBM, not latency. NT changes the read transaction type (no cache
// allocation for zero-reuse streams) — the last untested path knob.
__global__ __launch_bounds__(BLOCK, 8) void geo_loss_kernel(
        const vf4* __restrict__ a,
        const vf4* __restrict__ idd,
        float* __restrict__ partials, int n, int ntiles) {
    const int tid = threadIdx.x;
    float acc = 0.0f;

    for (int t = blockIdx.x; t < ntiles; t += gridDim.x) {
        const int base = t * TILE + tid;
        if (base + (UNROLL - 1) * BLOCK < n) {
            vf4 qa[UNROLL], qb[UNROLL];
            #pragma unroll
            for (int k = 0; k < UNROLL; k++) {
                qa[k] = __builtin_nontemporal_load(&a[base + k * BLOCK]);
                qb[k] = __builtin_nontemporal_load(&idd[base + k * BLOCK]);
            }
            #pragma unroll
            for (int k = 0; k < UNROLL; k++) acc += theta_sq(qa[k], qb[k]);
        } else {
            for (int k = 0; k < UNROLL; k++) {
                int idx = base + k * BLOCK;
                if (idx < n) acc += theta_sq(a[idx], idd[idx]);
            }
        }
    }

    // wave-64 reduction
    #pragma unroll
    for (int off = 32; off > 0; off >>= 1)
        acc += __shfl_down(acc, off, 64);
    __shared__ float smem[BLOCK / 64];
    int lane = tid & 63;
    int wid  = tid >> 6;
    if (lane == 0) smem[wid] = acc;
    __syncthreads();
    if (tid == 0) {
        float s = 0.0f;
        #pragma unroll
        for (int i = 0; i < BLOCK / 64; i++) s += smem[i];
        partials[blockIdx.x] = s;
    }
}

__global__ __launch_bounds__(256) void finalize_kernel(
        const float* __restrict__ partials,
        float* __restrict__ out, int nparts) {
    float acc = 0.0f;
    for (int i = threadIdx.x; i < nparts; i += 256)
        acc += partials[i];
    #pragma unroll
    for (int off = 32; off > 0; off >>= 1)
        acc += __shfl_down(acc, off, 64);
    __shared__ float smem[4];
    int lane = threadIdx.x & 63;
    int wid  = threadIdx.x >> 6;
    if (lane == 0) smem[wid] = acc;
    __syncthreads();
    if (threadIdx.x == 0)
        out[0] = sqrtf(smem[0] + smem[1] + smem[2] + smem[3]);
}

extern "C" void kernel_launch(void* const* d_in, const int* in_sizes, int n_in,
                              void* d_out, int out_size, void* d_ws, size_t ws_size,
                              hipStream_t stream) {
    const vf4* a   = (const vf4*)d_in[0];
    const vf4* idd = (const vf4*)d_in[1];
    int n = in_sizes[0] / 4;             // 4,000,000 quaternions
    float* ws = (float*)d_ws;

    int ntiles = (n + TILE - 1) / TILE;  // 3907
    int grid   = ntiles < MAX_GRID ? ntiles : MAX_GRID;
    geo_loss_kernel<<<grid, BLOCK, 0, stream>>>(a, idd, ws, n, ntiles);
    finalize_kernel<<<1, 256, 0, stream>>>(ws, (float*)d_out, grid);
}